// Round 9
// baseline (906.453 us; speedup 1.0000x reference)
//
#include <hip/hip_runtime.h>

#define N_NODES   50000
#define N_EDGES   800000
#define N_FEAT    128
#define HIDDEN    64
#define N_LAYERS  3
#define N_GRAPHS  512
#define N_CLASSES 10
#define BN_EPS    1e-5f
#define SCAN_BLK  196    // ceil(N_NODES/256)
#define LWAVES    8      // waves per block in enc/layer kernels (512 threads)
#define HP        32     // uints per bf16 h-row (64 cols * 2B = 128B)
#define NBLK      1024   // layer_kernel grid
#define NGRP      (N_NODES / 4)
#define QSCALE    65536.0f
#define QINV      (1.0f / 65536.0f)
#define SSCALE    1048576.0          // 2^20 stats fixed-point
#define SINV      (1.0 / 1048576.0)

// 16B-group XOR swizzle within a row: bank-conflict-minimal ds_read_b128
__device__ __forceinline__ int swz(int c, int g) { return g ^ (c & 15); }

// fp32 -> bf16 (RNE), returned in low 16 bits
__device__ __forceinline__ unsigned bf16rne(float x)
{
    unsigned u = __float_as_uint(x);
    return (u + 0x7fffu + ((u >> 16) & 1u)) >> 16;
}
// unpack bf16 pair: .x = low half (even col), .y = high half (odd col)
__device__ __forceinline__ float2 bf2(unsigned u)
{
    float2 r;
    r.x = __uint_as_float(u << 16);
    r.y = __uint_as_float(u & 0xffff0000u);
    return r;
}

// BN affine consts from int64 fixed-point stats (deterministic)
__device__ __forceinline__ void bn_const(const unsigned long long* stats,
                                         const float* gamma, const float* beta,
                                         int c, float& A, float& B)
{
    double m  = (double)(long long)stats[c]          * (SINV / (double)N_NODES);
    double e2 = (double)(long long)stats[HIDDEN + c] * (SINV / (double)N_NODES);
    float mean = (float)m;
    float var  = (float)(e2 - m * m);
    float inv  = rsqrtf(fmaxf(var, 0.f) + BN_EPS);
    A = inv * gamma[c];
    B = beta[c] - mean * A;
}

// ---------------- encoder: h = x @ enc_w + enc_b -> bf16 h -----------------
__global__ __launch_bounds__(512, 6) void enc_kernel(
    const float* __restrict__ x, const float* __restrict__ w,
    const float* __restrict__ b, unsigned* __restrict__ h,
    int* __restrict__ deg)
{
    __shared__ __align__(16) float wT[HIDDEN * N_FEAT];        // 32 KB swizzled
    __shared__ __align__(16) float xb[LWAVES][4][N_FEAT];      // 16 KB
    {   // fold: zero deg for the CSR histogram
        int g = blockIdx.x * 512 + threadIdx.x;
        if (g < N_NODES) deg[g] = 0;
    }
    for (int i = threadIdx.x; i < N_FEAT * HIDDEN; i += 512) {
        int k = i >> 6, c = i & 63;
        wT[c * 128 + swz(c, k >> 2) * 4 + (k & 3)] = w[i];
    }
    const int lane = threadIdx.x & 63;
    const int wv   = threadIdx.x >> 6;
    const int sz   = lane & 15;
    const int r2   = lane >> 5;          // 0..1
    const int cc   = (lane & 31) * 4;    // 0..124
    const float bias = b[lane];
    __syncthreads();
    const int nwaves = gridDim.x * LWAVES;
    for (int grp = blockIdx.x * LWAVES + wv; grp < NGRP; grp += nwaves) {
        const int nbase = grp * 4;
        float4 v0 = *(const float4*)&x[(size_t)(nbase + r2) * N_FEAT + cc];
        float4 v1 = *(const float4*)&x[(size_t)(nbase + 2 + r2) * N_FEAT + cc];
        *((float4*)&xb[wv][r2][cc])     = v0;
        *((float4*)&xb[wv][2 + r2][cc]) = v1;
        float o0 = bias, o1 = bias, o2 = bias, o3 = bias;
        #pragma unroll 8
        for (int kc = 0; kc < N_FEAT / 4; ++kc) {
            float4 w4 = *(const float4*)&wT[lane * 128 + ((kc ^ sz) << 2)];
            float4 z0 = *(const float4*)&xb[wv][0][4 * kc];
            float4 z1 = *(const float4*)&xb[wv][1][4 * kc];
            float4 z2 = *(const float4*)&xb[wv][2][4 * kc];
            float4 z3 = *(const float4*)&xb[wv][3][4 * kc];
            o0 = fmaf(w4.x, z0.x, fmaf(w4.y, z0.y, fmaf(w4.z, z0.z, fmaf(w4.w, z0.w, o0))));
            o1 = fmaf(w4.x, z1.x, fmaf(w4.y, z1.y, fmaf(w4.z, z1.z, fmaf(w4.w, z1.w, o1))));
            o2 = fmaf(w4.x, z2.x, fmaf(w4.y, z2.y, fmaf(w4.z, z2.z, fmaf(w4.w, z2.w, o2))));
            o3 = fmaf(w4.x, z3.x, fmaf(w4.y, z3.y, fmaf(w4.z, z3.z, fmaf(w4.w, z3.w, o3))));
        }
        float t0 = __shfl_xor(o0, 1), t1 = __shfl_xor(o1, 1);
        float t2 = __shfl_xor(o2, 1), t3 = __shfl_xor(o3, 1);
        if (!(lane & 1)) {
            int p = lane >> 1;
            h[(size_t)(nbase + 0) * HP + p] = bf16rne(o0) | (bf16rne(t0) << 16);
            h[(size_t)(nbase + 1) * HP + p] = bf16rne(o1) | (bf16rne(t1) << 16);
            h[(size_t)(nbase + 2) * HP + p] = bf16rne(o2) | (bf16rne(t2) << 16);
            h[(size_t)(nbase + 3) * HP + p] = bf16rne(o3) | (bf16rne(t3) << 16);
        }
    }
}

// ---------------- CSR build ------------------------------------------------
__global__ __launch_bounds__(256) void hist_kernel(const int* __restrict__ ei,
                                                   int* __restrict__ deg,
                                                   unsigned long long* __restrict__ stats,
                                                   int* __restrict__ wctr)
{
    if (blockIdx.x == 0) {   // fold: zero int64 stats + work counters
        for (int i = threadIdx.x; i < N_LAYERS * 2 * HIDDEN; i += 256) stats[i] = 0ull;
        if (threadIdx.x < N_LAYERS) wctr[threadIdx.x] = 0;
    }
    int e = blockIdx.x * 256 + threadIdx.x;
    if (e < N_EDGES) atomicAdd(&deg[ei[N_EDGES + e]], 1);
}

__global__ __launch_bounds__(256) void scan1_kernel(const int* __restrict__ deg,
                                                    int* __restrict__ row_start,
                                                    int* __restrict__ bsum)
{
    __shared__ int s[256];
    const int tid = threadIdx.x;
    const int gid = blockIdx.x * 256 + tid;
    int v = (gid < N_NODES) ? deg[gid] : 0;
    s[tid] = v;
    __syncthreads();
    for (int off = 1; off < 256; off <<= 1) {
        int t = (tid >= off) ? s[tid - off] : 0;
        __syncthreads();
        if (tid >= off) s[tid] += t;
        __syncthreads();
    }
    if (gid < N_NODES) row_start[gid] = s[tid] - v;
    if (tid == 255) bsum[blockIdx.x] = s[255];
}

__global__ __launch_bounds__(256) void scan2_kernel(int* __restrict__ bsum,
                                                    int* __restrict__ row_start)
{
    __shared__ int s[256];
    const int tid = threadIdx.x;
    int v = (tid < SCAN_BLK) ? bsum[tid] : 0;
    s[tid] = v;
    __syncthreads();
    for (int off = 1; off < 256; off <<= 1) {
        int t = (tid >= off) ? s[tid - off] : 0;
        __syncthreads();
        if (tid >= off) s[tid] += t;
        __syncthreads();
    }
    if (tid < SCAN_BLK) bsum[tid] = s[tid] - v;
    if (tid == 255) row_start[N_NODES] = s[255];
}

__global__ __launch_bounds__(256) void scan3_kernel(int* __restrict__ row_start,
                                                    const int* __restrict__ bsum,
                                                    int* __restrict__ cursor)
{
    int gid = blockIdx.x * 256 + threadIdx.x;
    if (gid < N_NODES) {
        int v = row_start[gid] + bsum[blockIdx.x];
        row_start[gid] = v;
        cursor[gid] = v;
    }
}

__global__ __launch_bounds__(256) void fill_kernel(const int* __restrict__ ei,
                                                   int* __restrict__ cursor,
                                                   int* __restrict__ csr_src)
{
    int e = blockIdx.x * 256 + threadIdx.x;
    if (e >= N_EDGES) return;
    int d = ei[N_EDGES + e];
    int pos = atomicAdd(&cursor[d], 1);
    csr_src[pos] = ei[e];
}

// ---------------- fused GIN layer (bf16 h, BN pre-applied) ------------------
// dynamic work-stealing (global counter); int32 fixed-point gather accumulate
// (permutation-invariant); BN stats via int64 fixed-point atomics (exact,
// order-free) -> fully deterministic under dynamic scheduling.
__global__ __launch_bounds__(512, 8) void layer_kernel(
    const unsigned* __restrict__ hin, const int* __restrict__ csr_src,
    const int* __restrict__ row_start, int* __restrict__ wctr,
    const float* __restrict__ eps, int layer,
    const float* __restrict__ w1, const float* __restrict__ b1,
    const float* __restrict__ w2, const float* __restrict__ b2,
    unsigned* __restrict__ hout, unsigned long long* __restrict__ stats_cur)
{
    __shared__ __align__(16) float wT1[HIDDEN * HIDDEN];       // 16 KB swizzled
    __shared__ __align__(16) float wT2[HIDDEN * HIDDEN];       // 16 KB swizzled
    __shared__ __align__(16) float zb[LWAVES][4][HIDDEN];      // 8 KB wave-private
    for (int i = threadIdx.x; i < HIDDEN * HIDDEN; i += 512) {
        int k = i >> 6, c = i & 63;
        int dst = c * 64 + swz(c, k >> 2) * 4 + (k & 3);
        wT1[dst] = w1[i];
        wT2[dst] = w2[i];
    }
    const int lane = threadIdx.x & 63;
    const int wv   = threadIdx.x >> 6;
    const int o    = lane >> 3;          // 0..7: row within oct
    const int c8   = (lane & 7) * 4;     // uint offset in row (8 bf16 cols)
    const int cb   = c8 * 2;
    const int sz   = lane & 15;
    const float sf  = 1.0f + eps[layer];
    const float b1c = b1[lane], b2c = b2[lane];
    __syncthreads();

    long long sAcc = 0, s2Acc = 0;
    for (;;) {
        int grp = 0;
        if (lane == 0) grp = atomicAdd(wctr, 1);
        grp = __shfl(grp, 0);
        if (grp >= NGRP) break;
        const int nbase = grp * 4;
        #pragma unroll
        for (int n = 0; n < 4; ++n) {
            const int node = nbase + n;
            const int s0 = row_start[node];
            const int s1 = row_start[node + 1];
            int a[8];
            #pragma unroll
            for (int t = 0; t < 8; ++t) a[t] = 0;
            for (int jb = s0; jb < s1; jb += 64) {
                int m = s1 - jb; if (m > 64) m = 64;
                int idx = csr_src[jb + (lane < m ? lane : m - 1)];
                int mm = m & ~7;
                for (int j = 0; j < mm; j += 8) {
                    int i = __shfl(idx, j + o);
                    uint4 u = *(const uint4*)&hin[(size_t)i * HP + c8];
                    float2 f0 = bf2(u.x), f1 = bf2(u.y), f2 = bf2(u.z), f3 = bf2(u.w);
                    a[0] += (int)(f0.x * QSCALE); a[1] += (int)(f0.y * QSCALE);
                    a[2] += (int)(f1.x * QSCALE); a[3] += (int)(f1.y * QSCALE);
                    a[4] += (int)(f2.x * QSCALE); a[5] += (int)(f2.y * QSCALE);
                    a[6] += (int)(f3.x * QSCALE); a[7] += (int)(f3.y * QSCALE);
                }
                int r8 = m & 7;
                if (r8) {
                    int sl = mm + o;
                    int i = __shfl(idx, sl < m ? sl : m - 1);
                    if (o < r8) {
                        uint4 u = *(const uint4*)&hin[(size_t)i * HP + c8];
                        float2 f0 = bf2(u.x), f1 = bf2(u.y), f2 = bf2(u.z), f3 = bf2(u.w);
                        a[0] += (int)(f0.x * QSCALE); a[1] += (int)(f0.y * QSCALE);
                        a[2] += (int)(f1.x * QSCALE); a[3] += (int)(f1.y * QSCALE);
                        a[4] += (int)(f2.x * QSCALE); a[5] += (int)(f2.y * QSCALE);
                        a[6] += (int)(f3.x * QSCALE); a[7] += (int)(f3.y * QSCALE);
                    }
                }
            }
            #pragma unroll
            for (int t = 0; t < 8; ++t) {
                a[t] += __shfl_xor(a[t], 8);
                a[t] += __shfl_xor(a[t], 16);
                a[t] += __shfl_xor(a[t], 32);
            }
            if (o == 0) {
                uint4 su = *(const uint4*)&hin[(size_t)node * HP + c8];
                float2 g0 = bf2(su.x), g1 = bf2(su.y), g2 = bf2(su.z), g3 = bf2(su.w);
                float svv[8] = {g0.x, g0.y, g1.x, g1.y, g2.x, g2.y, g3.x, g3.y};
                float zo[8];
                #pragma unroll
                for (int t = 0; t < 8; ++t)
                    zo[t] = fmaf(sf, svv[t], (float)a[t] * QINV);
                float4 q0 = {zo[0], zo[1], zo[2], zo[3]};
                float4 q1 = {zo[4], zo[5], zo[6], zo[7]};
                *((float4*)&zb[wv][n][cb])     = q0;
                *((float4*)&zb[wv][n][cb + 4]) = q1;
            }
        }
        // ---- MLP1: o = relu(z @ w1 + b1) ----
        float o0 = b1c, o1 = b1c, o2 = b1c, o3 = b1c;
        #pragma unroll 4
        for (int kc = 0; kc < HIDDEN / 4; ++kc) {
            float4 w4 = *(const float4*)&wT1[lane * 64 + ((kc ^ sz) << 2)];
            float4 z0 = *(const float4*)&zb[wv][0][4 * kc];
            float4 z1 = *(const float4*)&zb[wv][1][4 * kc];
            float4 z2 = *(const float4*)&zb[wv][2][4 * kc];
            float4 z3 = *(const float4*)&zb[wv][3][4 * kc];
            o0 = fmaf(w4.x, z0.x, fmaf(w4.y, z0.y, fmaf(w4.z, z0.z, fmaf(w4.w, z0.w, o0))));
            o1 = fmaf(w4.x, z1.x, fmaf(w4.y, z1.y, fmaf(w4.z, z1.z, fmaf(w4.w, z1.w, o1))));
            o2 = fmaf(w4.x, z2.x, fmaf(w4.y, z2.y, fmaf(w4.z, z2.z, fmaf(w4.w, z2.w, o2))));
            o3 = fmaf(w4.x, z3.x, fmaf(w4.y, z3.y, fmaf(w4.z, z3.z, fmaf(w4.w, z3.w, o3))));
        }
        zb[wv][0][lane] = fmaxf(o0, 0.f);
        zb[wv][1][lane] = fmaxf(o1, 0.f);
        zb[wv][2][lane] = fmaxf(o2, 0.f);
        zb[wv][3][lane] = fmaxf(o3, 0.f);
        // ---- MLP2: p = y @ w2 + b2 ----
        float p0 = b2c, p1 = b2c, p2 = b2c, p3 = b2c;
        #pragma unroll 4
        for (int kc = 0; kc < HIDDEN / 4; ++kc) {
            float4 w4 = *(const float4*)&wT2[lane * 64 + ((kc ^ sz) << 2)];
            float4 z0 = *(const float4*)&zb[wv][0][4 * kc];
            float4 z1 = *(const float4*)&zb[wv][1][4 * kc];
            float4 z2 = *(const float4*)&zb[wv][2][4 * kc];
            float4 z3 = *(const float4*)&zb[wv][3][4 * kc];
            p0 = fmaf(w4.x, z0.x, fmaf(w4.y, z0.y, fmaf(w4.z, z0.z, fmaf(w4.w, z0.w, p0))));
            p1 = fmaf(w4.x, z1.x, fmaf(w4.y, z1.y, fmaf(w4.z, z1.z, fmaf(w4.w, z1.w, p1))));
            p2 = fmaf(w4.x, z2.x, fmaf(w4.y, z2.y, fmaf(w4.z, z2.z, fmaf(w4.w, z2.w, p2))));
            p3 = fmaf(w4.x, z3.x, fmaf(w4.y, z3.y, fmaf(w4.z, z3.z, fmaf(w4.w, z3.w, p3))));
        }
        float t0 = __shfl_xor(p0, 1), t1 = __shfl_xor(p1, 1);
        float t2 = __shfl_xor(p2, 1), t3 = __shfl_xor(p3, 1);
        if (!(lane & 1)) {
            int p = lane >> 1;
            hout[(size_t)(nbase + 0) * HP + p] = bf16rne(p0) | (bf16rne(t0) << 16);
            hout[(size_t)(nbase + 1) * HP + p] = bf16rne(p1) | (bf16rne(t1) << 16);
            hout[(size_t)(nbase + 2) * HP + p] = bf16rne(p2) | (bf16rne(t2) << 16);
            hout[(size_t)(nbase + 3) * HP + p] = bf16rne(p3) | (bf16rne(t3) << 16);
        }
        // per-group stats in int64 fixed-point (fixed intra-group fp order)
        float g1 = (p0 + p1) + (p2 + p3);
        float g2 = (p0 * p0 + p1 * p1) + (p2 * p2 + p3 * p3);
        sAcc  += (long long)((double)g1 * SSCALE);
        s2Acc += (long long)((double)g2 * SSCALE);
    }
    // ---- block-level int64 reduction (exact) + one atomic per col ----
    __syncthreads();
    long long* red = (long long*)&zb[0][0][0];   // 1024 * 8B = 8 KB
    red[threadIdx.x]       = sAcc;
    red[512 + threadIdx.x] = s2Acc;
    __syncthreads();
    if (wv == 0) {
        long long ts = 0, ts2 = 0;
        #pragma unroll
        for (int wq = 0; wq < LWAVES; ++wq) {
            ts  += red[wq * 64 + lane];
            ts2 += red[512 + wq * 64 + lane];
        }
        atomicAdd((unsigned long long*)&stats_cur[lane],          (unsigned long long)ts);
        atomicAdd((unsigned long long*)&stats_cur[HIDDEN + lane], (unsigned long long)ts2);
    }
}

// ---------------- BN+ReLU applied once, in place (bf16) ---------------------
__global__ __launch_bounds__(512) void bn_apply_kernel(
    unsigned* __restrict__ h, const unsigned long long* __restrict__ stats,
    const float* __restrict__ gamma, const float* __restrict__ beta)
{
    int gid = blockIdx.x * 512 + threadIdx.x;
    if (gid >= N_NODES * 8) return;          // one uint4 (8 cols) per thread
    const int cb = (gid & 7) * 8;
    float A[8], B[8];
    #pragma unroll
    for (int t = 0; t < 8; ++t) bn_const(stats, gamma, beta, cb + t, A[t], B[t]);
    uint4 u = *((const uint4*)h + gid);
    float2 f0 = bf2(u.x), f1 = bf2(u.y), f2 = bf2(u.z), f3 = bf2(u.w);
    float v[8] = {f0.x, f0.y, f1.x, f1.y, f2.x, f2.y, f3.x, f3.y};
    unsigned w[4];
    #pragma unroll
    for (int t = 0; t < 4; ++t) {
        float lo = fmaxf(fmaf(v[2 * t],     A[2 * t],     B[2 * t]),     0.f);
        float hi = fmaxf(fmaf(v[2 * t + 1], A[2 * t + 1], B[2 * t + 1]), 0.f);
        w[t] = bf16rne(lo) | (bf16rne(hi) << 16);
    }
    uint4 ov = {w[0], w[1], w[2], w[3]};
    *((uint4*)h + gid) = ov;
}

__device__ __forceinline__ int lbound(const int* __restrict__ a, int n, int v)
{
    int lo = 0, hi = n;
    while (lo < hi) { int m = (lo + hi) >> 1; if (a[m] < v) lo = m + 1; else hi = m; }
    return lo;
}

// ---------------- mean pool per graph + final linear (fused) ---------------
__global__ __launch_bounds__(256) void pool_out_kernel(
    const unsigned* __restrict__ hpre, const int* __restrict__ batch,
    const unsigned long long* __restrict__ stats, const float* __restrict__ gamma,
    const float* __restrict__ beta, const float* __restrict__ lw,
    const float* __restrict__ lb, float* __restrict__ out)
{
    __shared__ int bounds[2];
    __shared__ float red[256];
    __shared__ float pv[64];
    const int g = blockIdx.x;
    if (threadIdx.x < 2)
        bounds[threadIdx.x] = lbound(batch, N_NODES, g + threadIdx.x);
    __syncthreads();
    const int start = bounds[0], end = bounds[1];
    const int col = threadIdx.x & 63;
    const int row = threadIdx.x >> 6;
    float A, B;
    bn_const(stats, gamma, beta, col, A, B);
    float s = 0.f;
    for (int r = start + row; r < end; r += 4) {
        unsigned u = hpre[(size_t)r * HP + (col >> 1)];
        float v = (col & 1) ? __uint_as_float(u & 0xffff0000u)
                            : __uint_as_float(u << 16);
        s += fmaxf(fmaf(v, A, B), 0.f);
    }
    red[threadIdx.x] = s;
    __syncthreads();
    if (row == 0) {
        float t = red[col] + red[64 + col] + red[128 + col] + red[192 + col];
        pv[col] = t / fmaxf((float)(end - start), 1.0f);
    }
    __syncthreads();
    if (threadIdx.x < N_CLASSES) {
        float acc = lb[threadIdx.x];
        #pragma unroll 16
        for (int j = 0; j < HIDDEN; ++j)
            acc = fmaf(pv[j], lw[j * N_CLASSES + threadIdx.x], acc);
        out[g * N_CLASSES + threadIdx.x] = acc;
    }
}

extern "C" void kernel_launch(void* const* d_in, const int* in_sizes, int n_in,
                              void* d_out, int out_size, void* d_ws, size_t ws_size,
                              hipStream_t stream)
{
    const float* x       = (const float*)d_in[0];
    const int*   ei      = (const int*)d_in[1];   // [2, N_EDGES]: src then dst
    const int*   batch   = (const int*)d_in[2];
    const float* enc_w   = (const float*)d_in[3];
    const float* enc_b   = (const float*)d_in[4];
    const float* eps     = (const float*)d_in[5];
    const float* conv_w1 = (const float*)d_in[6];
    const float* conv_b1 = (const float*)d_in[7];
    const float* conv_w2 = (const float*)d_in[8];
    const float* conv_b2 = (const float*)d_in[9];
    const float* bn_g    = (const float*)d_in[10];
    const float* bn_b    = (const float*)d_in[11];
    const float* lin_w   = (const float*)d_in[12];
    const float* lin_b   = (const float*)d_in[13];
    float* out = (float*)d_out;

    char* ws = (char*)d_ws;
    const size_t HB = (size_t)N_NODES * HP * sizeof(unsigned);  // 6.4 MB bf16 rows
    size_t off = 0;
    unsigned* P    = (unsigned*)(ws + off); off += HB;       // ping
    unsigned* Q    = (unsigned*)(ws + off); off += HB;       // pong
    unsigned long long* stats64 = (unsigned long long*)(ws + off);
    off += N_LAYERS * 2 * HIDDEN * sizeof(unsigned long long);
    int* wctr      = (int*)(ws + off); off += 16 * sizeof(int);
    int* deg       = (int*)(ws + off); off += 50176 * sizeof(int);
    int* row_start = (int*)(ws + off); off += 50176 * sizeof(int);   // N_NODES+1 used
    int* cursor    = (int*)(ws + off); off += 50176 * sizeof(int);
    int* bsum      = (int*)(ws + off); off += 256 * sizeof(int);
    int* csr_src   = (int*)(ws + off); off += (size_t)N_EDGES * sizeof(int);

    // enc zeroes deg; hist zeroes stats64 + work counters (stream-ordered)
    enc_kernel<<<768, 512, 0, stream>>>(x, enc_w, enc_b, P, deg);

    hist_kernel<<<(N_EDGES + 255) / 256, 256, 0, stream>>>(ei, deg, stats64, wctr);
    scan1_kernel<<<SCAN_BLK, 256, 0, stream>>>(deg, row_start, bsum);
    scan2_kernel<<<1, 256, 0, stream>>>(bsum, row_start);
    scan3_kernel<<<SCAN_BLK, 256, 0, stream>>>(row_start, bsum, cursor);
    fill_kernel<<<(N_EDGES + 255) / 256, 256, 0, stream>>>(ei, cursor, csr_src);

    const int bn_grid = (N_NODES * 8 + 511) / 512;
    const unsigned* curin = P;
    unsigned* curout = Q;
    for (int l = 0; l < N_LAYERS; ++l) {
        const float* w1 = conv_w1 + (size_t)l * HIDDEN * HIDDEN;
        const float* b1 = conv_b1 + (size_t)l * HIDDEN;
        const float* w2 = conv_w2 + (size_t)l * HIDDEN * HIDDEN;
        const float* b2 = conv_b2 + (size_t)l * HIDDEN;
        layer_kernel<<<NBLK, 512, 0, stream>>>(
            curin, csr_src, row_start, wctr + l, eps, l,
            w1, b1, w2, b2, curout, stats64 + (size_t)l * 2 * HIDDEN);
        if (l < N_LAYERS - 1)   // pre-apply BN+ReLU for the next layer's gather
            bn_apply_kernel<<<bn_grid, 512, 0, stream>>>(
                curout, stats64 + (size_t)l * 2 * HIDDEN,
                bn_g + (size_t)l * HIDDEN, bn_b + (size_t)l * HIDDEN);
        const unsigned* t = curout; curout = (unsigned*)curin; curin = t;
    }
    // after 3 layers: final pre-BN activations are in Q

    pool_out_kernel<<<N_GRAPHS, 256, 0, stream>>>(
        Q, batch, stats64 + (size_t)(N_LAYERS - 1) * 2 * HIDDEN,
        bn_g + (size_t)(N_LAYERS - 1) * HIDDEN, bn_b + (size_t)(N_LAYERS - 1) * HIDDEN,
        lin_w, lin_b, out);
}

// Round 10
// 338.845 us; speedup vs baseline: 2.6751x; 2.6751x over previous
//
#include <hip/hip_runtime.h>

#define N_NODES   50000
#define N_EDGES   800000
#define N_FEAT    128
#define HIDDEN    64
#define N_LAYERS  3
#define N_GRAPHS  512
#define N_CLASSES 10
#define BN_EPS    1e-5f
#define SCAN_BLK  196    // ceil(N_NODES/256)
#define LWAVES    8      // waves per block in enc/layer kernels (512 threads)
#define HP        32     // uints per bf16 h-row (64 cols * 2B = 128B)
#define NBLK      782    // 6256 waves -> 12500 groups / 6256 ~= 2.0 (99% balance)
#define NGRP      (N_NODES / 4)
#define QSCALE    65536.0f
#define QINV      (1.0f / 65536.0f)
#define SSCALE    1048576.0          // 2^20 stats fixed-point
#define SINV      (1.0 / 1048576.0)

// 16B-group XOR swizzle within a row: bank-conflict-minimal ds_read_b128
__device__ __forceinline__ int swz(int c, int g) { return g ^ (c & 15); }

// fp32 -> bf16 (RNE), returned in low 16 bits
__device__ __forceinline__ unsigned bf16rne(float x)
{
    unsigned u = __float_as_uint(x);
    return (u + 0x7fffu + ((u >> 16) & 1u)) >> 16;
}
// unpack bf16 pair: .x = low half (even col), .y = high half (odd col)
__device__ __forceinline__ float2 bf2(unsigned u)
{
    float2 r;
    r.x = __uint_as_float(u << 16);
    r.y = __uint_as_float(u & 0xffff0000u);
    return r;
}

// BN affine consts from int64 fixed-point stats (deterministic)
__device__ __forceinline__ void bn_const(const unsigned long long* stats,
                                         const float* gamma, const float* beta,
                                         int c, float& A, float& B)
{
    double m  = (double)(long long)stats[c]          * (SINV / (double)N_NODES);
    double e2 = (double)(long long)stats[HIDDEN + c] * (SINV / (double)N_NODES);
    float mean = (float)m;
    float var  = (float)(e2 - m * m);
    float inv  = rsqrtf(fmaxf(var, 0.f) + BN_EPS);
    A = inv * gamma[c];
    B = beta[c] - mean * A;
}

// ---------------- encoder: h = x @ enc_w + enc_b -> bf16 h -----------------
__global__ __launch_bounds__(512, 6) void enc_kernel(
    const float* __restrict__ x, const float* __restrict__ w,
    const float* __restrict__ b, unsigned* __restrict__ h,
    int* __restrict__ deg)
{
    __shared__ __align__(16) float wT[HIDDEN * N_FEAT];        // 32 KB swizzled
    __shared__ __align__(16) float xb[LWAVES][4][N_FEAT];      // 16 KB
    {   // fold: zero deg for the CSR histogram
        int g = blockIdx.x * 512 + threadIdx.x;
        if (g < N_NODES) deg[g] = 0;
    }
    for (int i = threadIdx.x; i < N_FEAT * HIDDEN; i += 512) {
        int k = i >> 6, c = i & 63;
        wT[c * 128 + swz(c, k >> 2) * 4 + (k & 3)] = w[i];
    }
    const int lane = threadIdx.x & 63;
    const int wv   = threadIdx.x >> 6;
    const int sz   = lane & 15;
    const int r2   = lane >> 5;          // 0..1
    const int cc   = (lane & 31) * 4;    // 0..124
    const float bias = b[lane];
    __syncthreads();
    const int nwaves = gridDim.x * LWAVES;
    for (int grp = blockIdx.x * LWAVES + wv; grp < NGRP; grp += nwaves) {
        const int nbase = grp * 4;
        float4 v0 = *(const float4*)&x[(size_t)(nbase + r2) * N_FEAT + cc];
        float4 v1 = *(const float4*)&x[(size_t)(nbase + 2 + r2) * N_FEAT + cc];
        *((float4*)&xb[wv][r2][cc])     = v0;
        *((float4*)&xb[wv][2 + r2][cc]) = v1;
        float o0 = bias, o1 = bias, o2 = bias, o3 = bias;
        #pragma unroll 8
        for (int kc = 0; kc < N_FEAT / 4; ++kc) {
            float4 w4 = *(const float4*)&wT[lane * 128 + ((kc ^ sz) << 2)];
            float4 z0 = *(const float4*)&xb[wv][0][4 * kc];
            float4 z1 = *(const float4*)&xb[wv][1][4 * kc];
            float4 z2 = *(const float4*)&xb[wv][2][4 * kc];
            float4 z3 = *(const float4*)&xb[wv][3][4 * kc];
            o0 = fmaf(w4.x, z0.x, fmaf(w4.y, z0.y, fmaf(w4.z, z0.z, fmaf(w4.w, z0.w, o0))));
            o1 = fmaf(w4.x, z1.x, fmaf(w4.y, z1.y, fmaf(w4.z, z1.z, fmaf(w4.w, z1.w, o1))));
            o2 = fmaf(w4.x, z2.x, fmaf(w4.y, z2.y, fmaf(w4.z, z2.z, fmaf(w4.w, z2.w, o2))));
            o3 = fmaf(w4.x, z3.x, fmaf(w4.y, z3.y, fmaf(w4.z, z3.z, fmaf(w4.w, z3.w, o3))));
        }
        float t0 = __shfl_xor(o0, 1), t1 = __shfl_xor(o1, 1);
        float t2 = __shfl_xor(o2, 1), t3 = __shfl_xor(o3, 1);
        if (!(lane & 1)) {
            int p = lane >> 1;
            h[(size_t)(nbase + 0) * HP + p] = bf16rne(o0) | (bf16rne(t0) << 16);
            h[(size_t)(nbase + 1) * HP + p] = bf16rne(o1) | (bf16rne(t1) << 16);
            h[(size_t)(nbase + 2) * HP + p] = bf16rne(o2) | (bf16rne(t2) << 16);
            h[(size_t)(nbase + 3) * HP + p] = bf16rne(o3) | (bf16rne(t3) << 16);
        }
    }
}

// ---------------- CSR build ------------------------------------------------
__global__ __launch_bounds__(256) void hist_kernel(const int* __restrict__ ei,
                                                   int* __restrict__ deg,
                                                   unsigned long long* __restrict__ stats)
{
    if (blockIdx.x == 0) {   // fold: zero int64 stats
        for (int i = threadIdx.x; i < N_LAYERS * 2 * HIDDEN; i += 256) stats[i] = 0ull;
    }
    int e = blockIdx.x * 256 + threadIdx.x;
    if (e < N_EDGES) atomicAdd(&deg[ei[N_EDGES + e]], 1);
}

__global__ __launch_bounds__(256) void scan1_kernel(const int* __restrict__ deg,
                                                    int* __restrict__ row_start,
                                                    int* __restrict__ bsum)
{
    __shared__ int s[256];
    const int tid = threadIdx.x;
    const int gid = blockIdx.x * 256 + tid;
    int v = (gid < N_NODES) ? deg[gid] : 0;
    s[tid] = v;
    __syncthreads();
    for (int off = 1; off < 256; off <<= 1) {
        int t = (tid >= off) ? s[tid - off] : 0;
        __syncthreads();
        if (tid >= off) s[tid] += t;
        __syncthreads();
    }
    if (gid < N_NODES) row_start[gid] = s[tid] - v;
    if (tid == 255) bsum[blockIdx.x] = s[255];
}

__global__ __launch_bounds__(256) void scan2_kernel(int* __restrict__ bsum,
                                                    int* __restrict__ row_start)
{
    __shared__ int s[256];
    const int tid = threadIdx.x;
    int v = (tid < SCAN_BLK) ? bsum[tid] : 0;
    s[tid] = v;
    __syncthreads();
    for (int off = 1; off < 256; off <<= 1) {
        int t = (tid >= off) ? s[tid - off] : 0;
        __syncthreads();
        if (tid >= off) s[tid] += t;
        __syncthreads();
    }
    if (tid < SCAN_BLK) bsum[tid] = s[tid] - v;
    if (tid == 255) row_start[N_NODES] = s[255];
}

__global__ __launch_bounds__(256) void scan3_kernel(int* __restrict__ row_start,
                                                    const int* __restrict__ bsum,
                                                    int* __restrict__ cursor)
{
    int gid = blockIdx.x * 256 + threadIdx.x;
    if (gid < N_NODES) {
        int v = row_start[gid] + bsum[blockIdx.x];
        row_start[gid] = v;
        cursor[gid] = v;
    }
}

__global__ __launch_bounds__(256) void fill_kernel(const int* __restrict__ ei,
                                                   int* __restrict__ cursor,
                                                   int* __restrict__ csr_src)
{
    int e = blockIdx.x * 256 + threadIdx.x;
    if (e >= N_EDGES) return;
    int d = ei[N_EDGES + e];
    int pos = atomicAdd(&cursor[d], 1);
    csr_src[pos] = ei[e];
}

// ---------------- fused GIN layer (bf16 h, BN pre-applied) ------------------
// STATIC balanced schedule: 6256 waves x ~2 groups each. int32 fixed-point
// gather accumulate (permutation-invariant) + int64 fixed-point stats atomics
// (order-free, exact) -> deterministic without any serializing counter.
__global__ __launch_bounds__(512, 8) void layer_kernel(
    const unsigned* __restrict__ hin, const int* __restrict__ csr_src,
    const int* __restrict__ row_start,
    const float* __restrict__ eps, int layer,
    const float* __restrict__ w1, const float* __restrict__ b1,
    const float* __restrict__ w2, const float* __restrict__ b2,
    unsigned* __restrict__ hout, unsigned long long* __restrict__ stats_cur)
{
    __shared__ __align__(16) float wT1[HIDDEN * HIDDEN];       // 16 KB swizzled
    __shared__ __align__(16) float wT2[HIDDEN * HIDDEN];       // 16 KB swizzled
    __shared__ __align__(16) float zb[LWAVES][4][HIDDEN];      // 8 KB wave-private
    for (int i = threadIdx.x; i < HIDDEN * HIDDEN; i += 512) {
        int k = i >> 6, c = i & 63;
        int dst = c * 64 + swz(c, k >> 2) * 4 + (k & 3);
        wT1[dst] = w1[i];
        wT2[dst] = w2[i];
    }
    const int lane = threadIdx.x & 63;
    const int wv   = threadIdx.x >> 6;
    const int o    = lane >> 3;          // 0..7: row within oct
    const int c8   = (lane & 7) * 4;     // uint offset in row (8 bf16 cols)
    const int cb   = c8 * 2;
    const int sz   = lane & 15;
    const float sf  = 1.0f + eps[layer];
    const float b1c = b1[lane], b2c = b2[lane];
    __syncthreads();

    long long sAcc = 0, s2Acc = 0;
    const int nwaves = gridDim.x * LWAVES;
    for (int grp = blockIdx.x * LWAVES + wv; grp < NGRP; grp += nwaves) {
        const int nbase = grp * 4;
        #pragma unroll
        for (int n = 0; n < 4; ++n) {
            const int node = nbase + n;
            const int s0 = row_start[node];
            const int s1 = row_start[node + 1];
            int a[8];
            #pragma unroll
            for (int t = 0; t < 8; ++t) a[t] = 0;
            for (int jb = s0; jb < s1; jb += 64) {
                int m = s1 - jb; if (m > 64) m = 64;
                int idx = csr_src[jb + (lane < m ? lane : m - 1)];
                int mm = m & ~7;
                for (int j = 0; j < mm; j += 8) {
                    int i = __shfl(idx, j + o);
                    uint4 u = *(const uint4*)&hin[(size_t)i * HP + c8];
                    float2 f0 = bf2(u.x), f1 = bf2(u.y), f2 = bf2(u.z), f3 = bf2(u.w);
                    a[0] += (int)(f0.x * QSCALE); a[1] += (int)(f0.y * QSCALE);
                    a[2] += (int)(f1.x * QSCALE); a[3] += (int)(f1.y * QSCALE);
                    a[4] += (int)(f2.x * QSCALE); a[5] += (int)(f2.y * QSCALE);
                    a[6] += (int)(f3.x * QSCALE); a[7] += (int)(f3.y * QSCALE);
                }
                int r8 = m & 7;
                if (r8) {
                    int sl = mm + o;
                    int i = __shfl(idx, sl < m ? sl : m - 1);
                    if (o < r8) {
                        uint4 u = *(const uint4*)&hin[(size_t)i * HP + c8];
                        float2 f0 = bf2(u.x), f1 = bf2(u.y), f2 = bf2(u.z), f3 = bf2(u.w);
                        a[0] += (int)(f0.x * QSCALE); a[1] += (int)(f0.y * QSCALE);
                        a[2] += (int)(f1.x * QSCALE); a[3] += (int)(f1.y * QSCALE);
                        a[4] += (int)(f2.x * QSCALE); a[5] += (int)(f2.y * QSCALE);
                        a[6] += (int)(f3.x * QSCALE); a[7] += (int)(f3.y * QSCALE);
                    }
                }
            }
            #pragma unroll
            for (int t = 0; t < 8; ++t) {
                a[t] += __shfl_xor(a[t], 8);
                a[t] += __shfl_xor(a[t], 16);
                a[t] += __shfl_xor(a[t], 32);
            }
            if (o == 0) {
                uint4 su = *(const uint4*)&hin[(size_t)node * HP + c8];
                float2 g0 = bf2(su.x), g1 = bf2(su.y), g2 = bf2(su.z), g3 = bf2(su.w);
                float svv[8] = {g0.x, g0.y, g1.x, g1.y, g2.x, g2.y, g3.x, g3.y};
                float zo[8];
                #pragma unroll
                for (int t = 0; t < 8; ++t)
                    zo[t] = fmaf(sf, svv[t], (float)a[t] * QINV);
                float4 q0 = {zo[0], zo[1], zo[2], zo[3]};
                float4 q1 = {zo[4], zo[5], zo[6], zo[7]};
                *((float4*)&zb[wv][n][cb])     = q0;
                *((float4*)&zb[wv][n][cb + 4]) = q1;
            }
        }
        // ---- MLP1: o = relu(z @ w1 + b1) ----
        float o0 = b1c, o1 = b1c, o2 = b1c, o3 = b1c;
        #pragma unroll 4
        for (int kc = 0; kc < HIDDEN / 4; ++kc) {
            float4 w4 = *(const float4*)&wT1[lane * 64 + ((kc ^ sz) << 2)];
            float4 z0 = *(const float4*)&zb[wv][0][4 * kc];
            float4 z1 = *(const float4*)&zb[wv][1][4 * kc];
            float4 z2 = *(const float4*)&zb[wv][2][4 * kc];
            float4 z3 = *(const float4*)&zb[wv][3][4 * kc];
            o0 = fmaf(w4.x, z0.x, fmaf(w4.y, z0.y, fmaf(w4.z, z0.z, fmaf(w4.w, z0.w, o0))));
            o1 = fmaf(w4.x, z1.x, fmaf(w4.y, z1.y, fmaf(w4.z, z1.z, fmaf(w4.w, z1.w, o1))));
            o2 = fmaf(w4.x, z2.x, fmaf(w4.y, z2.y, fmaf(w4.z, z2.z, fmaf(w4.w, z2.w, o2))));
            o3 = fmaf(w4.x, z3.x, fmaf(w4.y, z3.y, fmaf(w4.z, z3.z, fmaf(w4.w, z3.w, o3))));
        }
        zb[wv][0][lane] = fmaxf(o0, 0.f);
        zb[wv][1][lane] = fmaxf(o1, 0.f);
        zb[wv][2][lane] = fmaxf(o2, 0.f);
        zb[wv][3][lane] = fmaxf(o3, 0.f);
        // ---- MLP2: p = y @ w2 + b2 ----
        float p0 = b2c, p1 = b2c, p2 = b2c, p3 = b2c;
        #pragma unroll 4
        for (int kc = 0; kc < HIDDEN / 4; ++kc) {
            float4 w4 = *(const float4*)&wT2[lane * 64 + ((kc ^ sz) << 2)];
            float4 z0 = *(const float4*)&zb[wv][0][4 * kc];
            float4 z1 = *(const float4*)&zb[wv][1][4 * kc];
            float4 z2 = *(const float4*)&zb[wv][2][4 * kc];
            float4 z3 = *(const float4*)&zb[wv][3][4 * kc];
            p0 = fmaf(w4.x, z0.x, fmaf(w4.y, z0.y, fmaf(w4.z, z0.z, fmaf(w4.w, z0.w, p0))));
            p1 = fmaf(w4.x, z1.x, fmaf(w4.y, z1.y, fmaf(w4.z, z1.z, fmaf(w4.w, z1.w, p1))));
            p2 = fmaf(w4.x, z2.x, fmaf(w4.y, z2.y, fmaf(w4.z, z2.z, fmaf(w4.w, z2.w, p2))));
            p3 = fmaf(w4.x, z3.x, fmaf(w4.y, z3.y, fmaf(w4.z, z3.z, fmaf(w4.w, z3.w, p3))));
        }
        float t0 = __shfl_xor(p0, 1), t1 = __shfl_xor(p1, 1);
        float t2 = __shfl_xor(p2, 1), t3 = __shfl_xor(p3, 1);
        if (!(lane & 1)) {
            int p = lane >> 1;
            hout[(size_t)(nbase + 0) * HP + p] = bf16rne(p0) | (bf16rne(t0) << 16);
            hout[(size_t)(nbase + 1) * HP + p] = bf16rne(p1) | (bf16rne(t1) << 16);
            hout[(size_t)(nbase + 2) * HP + p] = bf16rne(p2) | (bf16rne(t2) << 16);
            hout[(size_t)(nbase + 3) * HP + p] = bf16rne(p3) | (bf16rne(t3) << 16);
        }
        // per-group stats in int64 fixed-point (fixed intra-group fp order)
        float g1 = (p0 + p1) + (p2 + p3);
        float g2 = (p0 * p0 + p1 * p1) + (p2 * p2 + p3 * p3);
        sAcc  += (long long)((double)g1 * SSCALE);
        s2Acc += (long long)((double)g2 * SSCALE);
    }
    // ---- block-level int64 reduction (exact) + one atomic per col ----
    __syncthreads();
    long long* red = (long long*)&zb[0][0][0];   // 1024 * 8B = 8 KB
    red[threadIdx.x]       = sAcc;
    red[512 + threadIdx.x] = s2Acc;
    __syncthreads();
    if (wv == 0) {
        long long ts = 0, ts2 = 0;
        #pragma unroll
        for (int wq = 0; wq < LWAVES; ++wq) {
            ts  += red[wq * 64 + lane];
            ts2 += red[512 + wq * 64 + lane];
        }
        atomicAdd((unsigned long long*)&stats_cur[lane],          (unsigned long long)ts);
        atomicAdd((unsigned long long*)&stats_cur[HIDDEN + lane], (unsigned long long)ts2);
    }
}

// ---------------- BN+ReLU applied once, in place (bf16) ---------------------
__global__ __launch_bounds__(512) void bn_apply_kernel(
    unsigned* __restrict__ h, const unsigned long long* __restrict__ stats,
    const float* __restrict__ gamma, const float* __restrict__ beta)
{
    int gid = blockIdx.x * 512 + threadIdx.x;
    if (gid >= N_NODES * 8) return;          // one uint4 (8 cols) per thread
    const int cb = (gid & 7) * 8;
    float A[8], B[8];
    #pragma unroll
    for (int t = 0; t < 8; ++t) bn_const(stats, gamma, beta, cb + t, A[t], B[t]);
    uint4 u = *((const uint4*)h + gid);
    float2 f0 = bf2(u.x), f1 = bf2(u.y), f2 = bf2(u.z), f3 = bf2(u.w);
    float v[8] = {f0.x, f0.y, f1.x, f1.y, f2.x, f2.y, f3.x, f3.y};
    unsigned w[4];
    #pragma unroll
    for (int t = 0; t < 4; ++t) {
        float lo = fmaxf(fmaf(v[2 * t],     A[2 * t],     B[2 * t]),     0.f);
        float hi = fmaxf(fmaf(v[2 * t + 1], A[2 * t + 1], B[2 * t + 1]), 0.f);
        w[t] = bf16rne(lo) | (bf16rne(hi) << 16);
    }
    uint4 ov = {w[0], w[1], w[2], w[3]};
    *((uint4*)h + gid) = ov;
}

__device__ __forceinline__ int lbound(const int* __restrict__ a, int n, int v)
{
    int lo = 0, hi = n;
    while (lo < hi) { int m = (lo + hi) >> 1; if (a[m] < v) lo = m + 1; else hi = m; }
    return lo;
}

// ---------------- mean pool per graph + final linear (fused) ---------------
__global__ __launch_bounds__(256) void pool_out_kernel(
    const unsigned* __restrict__ hpre, const int* __restrict__ batch,
    const unsigned long long* __restrict__ stats, const float* __restrict__ gamma,
    const float* __restrict__ beta, const float* __restrict__ lw,
    const float* __restrict__ lb, float* __restrict__ out)
{
    __shared__ int bounds[2];
    __shared__ float red[256];
    __shared__ float pv[64];
    const int g = blockIdx.x;
    if (threadIdx.x < 2)
        bounds[threadIdx.x] = lbound(batch, N_NODES, g + threadIdx.x);
    __syncthreads();
    const int start = bounds[0], end = bounds[1];
    const int col = threadIdx.x & 63;
    const int row = threadIdx.x >> 6;
    float A, B;
    bn_const(stats, gamma, beta, col, A, B);
    float s = 0.f;
    for (int r = start + row; r < end; r += 4) {
        unsigned u = hpre[(size_t)r * HP + (col >> 1)];
        float v = (col & 1) ? __uint_as_float(u & 0xffff0000u)
                            : __uint_as_float(u << 16);
        s += fmaxf(fmaf(v, A, B), 0.f);
    }
    red[threadIdx.x] = s;
    __syncthreads();
    if (row == 0) {
        float t = red[col] + red[64 + col] + red[128 + col] + red[192 + col];
        pv[col] = t / fmaxf((float)(end - start), 1.0f);
    }
    __syncthreads();
    if (threadIdx.x < N_CLASSES) {
        float acc = lb[threadIdx.x];
        #pragma unroll 16
        for (int j = 0; j < HIDDEN; ++j)
            acc = fmaf(pv[j], lw[j * N_CLASSES + threadIdx.x], acc);
        out[g * N_CLASSES + threadIdx.x] = acc;
    }
}

extern "C" void kernel_launch(void* const* d_in, const int* in_sizes, int n_in,
                              void* d_out, int out_size, void* d_ws, size_t ws_size,
                              hipStream_t stream)
{
    const float* x       = (const float*)d_in[0];
    const int*   ei      = (const int*)d_in[1];   // [2, N_EDGES]: src then dst
    const int*   batch   = (const int*)d_in[2];
    const float* enc_w   = (const float*)d_in[3];
    const float* enc_b   = (const float*)d_in[4];
    const float* eps     = (const float*)d_in[5];
    const float* conv_w1 = (const float*)d_in[6];
    const float* conv_b1 = (const float*)d_in[7];
    const float* conv_w2 = (const float*)d_in[8];
    const float* conv_b2 = (const float*)d_in[9];
    const float* bn_g    = (const float*)d_in[10];
    const float* bn_b    = (const float*)d_in[11];
    const float* lin_w   = (const float*)d_in[12];
    const float* lin_b   = (const float*)d_in[13];
    float* out = (float*)d_out;

    char* ws = (char*)d_ws;
    const size_t HB = (size_t)N_NODES * HP * sizeof(unsigned);  // 6.4 MB bf16 rows
    size_t off = 0;
    unsigned* P    = (unsigned*)(ws + off); off += HB;       // ping
    unsigned* Q    = (unsigned*)(ws + off); off += HB;       // pong
    unsigned long long* stats64 = (unsigned long long*)(ws + off);
    off += N_LAYERS * 2 * HIDDEN * sizeof(unsigned long long);
    int* deg       = (int*)(ws + off); off += 50176 * sizeof(int);
    int* row_start = (int*)(ws + off); off += 50176 * sizeof(int);   // N_NODES+1 used
    int* cursor    = (int*)(ws + off); off += 50176 * sizeof(int);
    int* bsum      = (int*)(ws + off); off += 256 * sizeof(int);
    int* csr_src   = (int*)(ws + off); off += (size_t)N_EDGES * sizeof(int);

    // enc zeroes deg; hist zeroes stats64 (stream-ordered before use)
    enc_kernel<<<768, 512, 0, stream>>>(x, enc_w, enc_b, P, deg);

    hist_kernel<<<(N_EDGES + 255) / 256, 256, 0, stream>>>(ei, deg, stats64);
    scan1_kernel<<<SCAN_BLK, 256, 0, stream>>>(deg, row_start, bsum);
    scan2_kernel<<<1, 256, 0, stream>>>(bsum, row_start);
    scan3_kernel<<<SCAN_BLK, 256, 0, stream>>>(row_start, bsum, cursor);
    fill_kernel<<<(N_EDGES + 255) / 256, 256, 0, stream>>>(ei, cursor, csr_src);

    const int bn_grid = (N_NODES * 8 + 511) / 512;
    const unsigned* curin = P;
    unsigned* curout = Q;
    for (int l = 0; l < N_LAYERS; ++l) {
        const float* w1 = conv_w1 + (size_t)l * HIDDEN * HIDDEN;
        const float* b1 = conv_b1 + (size_t)l * HIDDEN;
        const float* w2 = conv_w2 + (size_t)l * HIDDEN * HIDDEN;
        const float* b2 = conv_b2 + (size_t)l * HIDDEN;
        layer_kernel<<<NBLK, 512, 0, stream>>>(
            curin, csr_src, row_start, eps, l,
            w1, b1, w2, b2, curout, stats64 + (size_t)l * 2 * HIDDEN);
        if (l < N_LAYERS - 1)   // pre-apply BN+ReLU for the next layer's gather
            bn_apply_kernel<<<bn_grid, 512, 0, stream>>>(
                curout, stats64 + (size_t)l * 2 * HIDDEN,
                bn_g + (size_t)l * HIDDEN, bn_b + (size_t)l * HIDDEN);
        const unsigned* t = curout; curout = (unsigned*)curin; curin = t;
    }
    // after 3 layers: final pre-BN activations are in Q

    pool_out_kernel<<<N_GRAPHS, 256, 0, stream>>>(
        Q, batch, stats64 + (size_t)(N_LAYERS - 1) * 2 * HIDDEN,
        bn_g + (size_t)(N_LAYERS - 1) * HIDDEN, bn_b + (size_t)(N_LAYERS - 1) * HIDDEN,
        lin_w, lin_b, out);
}